// Round 1
// baseline (3183.844 us; speedup 1.0000x reference)
//
#include <hip/hip_runtime.h>

typedef __attribute__((ext_vector_type(4))) float f32x4;
typedef __attribute__((ext_vector_type(8))) short s16x8;
typedef __attribute__((ext_vector_type(4))) unsigned short u16x4;
typedef unsigned short u16;

// ---------- bf16 helpers (RNE, no NaN handling needed) ----------
__device__ inline u16 f2bf(float x) {
  unsigned u = __float_as_uint(x);
  return (u16)((u + 0x7fffu + ((u >> 16) & 1u)) >> 16);
}
__device__ inline float bf2f(u16 h) {
  return __uint_as_float(((unsigned)h) << 16);
}

// ---------- GEMM: C[M,N] = A[M,K] (bf16) @ (Wh+Wl)[N,K]^T (bf16 split) ----------
// block = 256 thr = 4 waves (2x2); per-wave FMxFN frags of 16x16; BK=32.
// flags: 0 = fp32 out, 1 = fp32 out + bias, 2 = bf16 out
template<int FM, int FN>
__global__ __launch_bounds__(256)
void gemm_bf(const u16* __restrict__ A, int lda,
             const u16* __restrict__ Wh, const u16* __restrict__ Wl, int ldw,
             void* __restrict__ Cv, int ldc, int K,
             const float* __restrict__ bias, int flags) {
  constexpr int BM = 32 * FM, BN = 32 * FN;
  __shared__ u16 lA[BM * 32];
  __shared__ u16 lWh[BN * 32];
  __shared__ u16 lWl[BN * 32];
  const int tid = threadIdx.x;
  const int m0 = blockIdx.y * BM, n0 = blockIdx.x * BN;
  const int wave = tid >> 6, lane = tid & 63;
  const int wr = (wave >> 1) * (16 * FM), wc = (wave & 1) * (16 * FN);
  const int fr = lane & 15, fq = lane >> 4;
  f32x4 acc[FM][FN] = {};
  for (int k0 = 0; k0 < K; k0 += 32) {
    __syncthreads();
    #pragma unroll
    for (int ci = tid; ci < BM * 4; ci += 256) {
      int row = ci >> 2, kc = ci & 3;
      s16x8 v = *reinterpret_cast<const s16x8*>(A + (size_t)(m0 + row) * lda + k0 + kc * 8);
      *reinterpret_cast<s16x8*>(&lA[row * 32 + ((kc ^ (row & 3)) * 8)]) = v;
    }
    #pragma unroll
    for (int ci = tid; ci < BN * 4; ci += 256) {
      int row = ci >> 2, kc = ci & 3;
      size_t go = (size_t)(n0 + row) * ldw + k0 + kc * 8;
      int so = row * 32 + ((kc ^ (row & 3)) * 8);
      *reinterpret_cast<s16x8*>(&lWh[so]) = *reinterpret_cast<const s16x8*>(Wh + go);
      *reinterpret_cast<s16x8*>(&lWl[so]) = *reinterpret_cast<const s16x8*>(Wl + go);
    }
    __syncthreads();
    s16x8 af[FM], bh[FN], bl[FN];
    #pragma unroll
    for (int mi = 0; mi < FM; ++mi) {
      int r = wr + mi * 16 + fr;
      af[mi] = *reinterpret_cast<const s16x8*>(&lA[r * 32 + ((fq ^ (r & 3)) * 8)]);
    }
    #pragma unroll
    for (int ni = 0; ni < FN; ++ni) {
      int r = wc + ni * 16 + fr;
      int so = r * 32 + ((fq ^ (r & 3)) * 8);
      bh[ni] = *reinterpret_cast<const s16x8*>(&lWh[so]);
      bl[ni] = *reinterpret_cast<const s16x8*>(&lWl[so]);
    }
    #pragma unroll
    for (int mi = 0; mi < FM; ++mi)
      #pragma unroll
      for (int ni = 0; ni < FN; ++ni) {
        acc[mi][ni] = __builtin_amdgcn_mfma_f32_16x16x32_bf16(af[mi], bh[ni], acc[mi][ni], 0, 0, 0);
        acc[mi][ni] = __builtin_amdgcn_mfma_f32_16x16x32_bf16(af[mi], bl[ni], acc[mi][ni], 0, 0, 0);
      }
  }
  if (flags == 2) {
    u16* Cb = (u16*)Cv;
    #pragma unroll
    for (int mi = 0; mi < FM; ++mi)
      #pragma unroll
      for (int ni = 0; ni < FN; ++ni) {
        int gm = m0 + wr + mi * 16 + fq * 4;
        int gn = n0 + wc + ni * 16 + fr;
        #pragma unroll
        for (int r = 0; r < 4; ++r)
          Cb[(size_t)(gm + r) * ldc + gn] = f2bf(acc[mi][ni][r]);
      }
  } else {
    float* C = (float*)Cv;
    #pragma unroll
    for (int mi = 0; mi < FM; ++mi)
      #pragma unroll
      for (int ni = 0; ni < FN; ++ni) {
        int gm = m0 + wr + mi * 16 + fq * 4;
        int gn = n0 + wc + ni * 16 + fr;
        float badd = (flags == 1) ? bias[gn] : 0.f;
        #pragma unroll
        for (int r = 0; r < 4; ++r)
          C[(size_t)(gm + r) * ldc + gn] = acc[mi][ni][r] + badd;
      }
  }
}

// ---------- weight conversion: fp32 -> bf16 hi/lo ----------
__global__ void k_wcvt(const float* __restrict__ s0, const float* __restrict__ s1,
                       const float* __restrict__ s2, const float* __restrict__ s3,
                       u16* __restrict__ wh, u16* __restrict__ wl) {
  int i4 = blockIdx.x * 256 + threadIdx.x;
  size_t idx = (size_t)i4 * 4;
  const float* s; size_t off;
  if (idx < 1048576)      { s = s0; off = idx; }
  else if (idx < 1572864) { s = s1; off = idx - 1048576; }
  else if (idx < 3670016) { s = s2; off = idx - 1572864; }
  else                    { s = s3; off = idx - 3670016; }
  f32x4 v = *reinterpret_cast<const f32x4*>(s + off);
  u16x4 hv, lv;
  #pragma unroll
  for (int j = 0; j < 4; ++j) {
    u16 hb = f2bf(v[j]);
    hv[j] = hb;
    lv[j] = f2bf(v[j] - bf2f(hb));
  }
  *reinterpret_cast<u16x4*>(wh + idx) = hv;
  *reinterpret_cast<u16x4*>(wl + idx) = lv;
}

__global__ void k_cvtsplit(const float* __restrict__ s, u16* __restrict__ wh, u16* __restrict__ wl) {
  int i4 = blockIdx.x * 256 + threadIdx.x;
  size_t idx = (size_t)i4 * 4;
  f32x4 v = *reinterpret_cast<const f32x4*>(s + idx);
  u16x4 hv, lv;
  #pragma unroll
  for (int j = 0; j < 4; ++j) {
    u16 hb = f2bf(v[j]);
    hv[j] = hb;
    lv[j] = f2bf(v[j] - bf2f(hb));
  }
  *reinterpret_cast<u16x4*>(wh + idx) = hv;
  *reinterpret_cast<u16x4*>(wl + idx) = lv;
}

__global__ void k_cvt(const float* __restrict__ s, u16* __restrict__ d) {
  int i4 = blockIdx.x * 256 + threadIdx.x;
  size_t idx = (size_t)i4 * 4;
  f32x4 v = *reinterpret_cast<const f32x4*>(s + idx);
  u16x4 o;
  #pragma unroll
  for (int j = 0; j < 4; ++j) o[j] = f2bf(v[j]);
  *reinterpret_cast<u16x4*>(d + idx) = o;
}

// ---------- residual add + rmsnorm (writes fp32 + bf16 normed) ----------
__global__ void k_addnorm(float* __restrict__ r, const float* __restrict__ h,
                          const float* __restrict__ w, float* __restrict__ o,
                          u16* __restrict__ ob) {
  int t = blockIdx.x, tid = threadIdx.x;
  size_t base = (size_t)t * 512;
  float s0 = r[base + tid] + h[base + tid];
  float s1 = r[base + 256 + tid] + h[base + 256 + tid];
  float ss = s0 * s0 + s1 * s1;
  for (int m = 32; m; m >>= 1) ss += __shfl_xor(ss, m);
  __shared__ float red[4];
  if ((tid & 63) == 0) red[tid >> 6] = ss;
  __syncthreads();
  float tot = red[0] + red[1] + red[2] + red[3];
  float sc = rsqrtf(tot * (1.f / 512.f) + 1e-5f);
  r[base + tid] = s0;
  r[base + 256 + tid] = s1;
  float o0 = s0 * sc * w[tid], o1 = s1 * sc * w[tid + 256];
  o[base + tid] = o0;
  o[base + 256 + tid] = o1;
  ob[base + tid] = f2bf(o0);
  ob[base + 256 + tid] = f2bf(o1);
}

// ---------- causal depthwise conv (4 taps) + silu ----------
__global__ void k_conv(const float* __restrict__ xz, const float* __restrict__ cw,
                       const float* __restrict__ cb, float* __restrict__ xc) {
  int idx = blockIdx.x * 256 + threadIdx.x;
  int t = idx >> 10, d = idx & 1023, l = t & 511;
  f32x4 w = *reinterpret_cast<const f32x4*>(cw + d * 4);
  float v = cb[d];
  #pragma unroll
  for (int j = 0; j < 4; ++j) {
    int lj = l - 3 + j;
    if (lj >= 0) v += w[j] * xz[(size_t)(t - 3 + j) * 2048 + d];
  }
  xc[idx] = v / (1.f + __expf(-v));
}

// ---------- x_proj: xdb[T,64] = xc[T,1024] @ xpw[64,1024]^T ----------
__global__ void k_xdb(const float* __restrict__ xc, const float* __restrict__ xpw,
                      float* __restrict__ xdb) {
  __shared__ float lx[4][1024];
  int tid = threadIdx.x;
  int t0 = blockIdx.x * 4;
  #pragma unroll
  for (int q = 0; q < 4; ++q)
    *reinterpret_cast<f32x4*>(&lx[q][tid * 4]) =
        *reinterpret_cast<const f32x4*>(xc + (size_t)(t0 + q) * 1024 + tid * 4);
  __syncthreads();
  int o = tid >> 2, p = tid & 3;
  const float* wr = xpw + (size_t)o * 1024 + p * 256;
  float a[4] = {0.f, 0.f, 0.f, 0.f};
  for (int kk = 0; kk < 256; kk += 4) {
    f32x4 w4 = *reinterpret_cast<const f32x4*>(wr + kk);
    #pragma unroll
    for (int tt = 0; tt < 4; ++tt) {
      f32x4 x4 = *reinterpret_cast<const f32x4*>(&lx[tt][p * 256 + kk]);
      a[tt] += w4[0] * x4[0] + w4[1] * x4[1] + w4[2] * x4[2] + w4[3] * x4[3];
    }
  }
  #pragma unroll
  for (int tt = 0; tt < 4; ++tt) {
    float v = a[tt];
    v += __shfl_xor(v, 1);
    v += __shfl_xor(v, 2);
    if (p == 0) xdb[(size_t)(t0 + tt) * 64 + o] = v;
  }
}

// ---------- dt = softplus(dt_r @ dtw^T + dtb) ----------
__global__ void k_dt(const float* __restrict__ xdb, const float* __restrict__ dtw,
                     const float* __restrict__ dtbias, float* __restrict__ dt) {
  __shared__ float lw[32][256];
  __shared__ float lx[8][32];
  int tid = threadIdx.x;
  int d0 = blockIdx.y * 256;
  int tg = blockIdx.x;
  #pragma unroll
  for (int q = 0; q < 8; ++q) {
    int idx = tid + q * 256;
    int d = idx >> 3, rq = idx & 7;
    f32x4 v = *reinterpret_cast<const f32x4*>(dtw + (size_t)(d0 + d) * 32 + rq * 4);
    lw[rq * 4 + 0][d] = v[0]; lw[rq * 4 + 1][d] = v[1];
    lw[rq * 4 + 2][d] = v[2]; lw[rq * 4 + 3][d] = v[3];
  }
  if (tid < 64) {
    int tt = tid >> 3, f4 = tid & 7;
    *reinterpret_cast<f32x4*>(&lx[tt][f4 * 4]) =
        *reinterpret_cast<const f32x4*>(xdb + (size_t)(tg * 8 + tt) * 64 + f4 * 4);
  }
  __syncthreads();
  float accv[8] = {};
  for (int r = 0; r < 32; ++r) {
    float wv = lw[r][tid];
    #pragma unroll
    for (int tt = 0; tt < 8; ++tt) accv[tt] += wv * lx[tt][r];
  }
  float bias = dtbias[d0 + tid];
  #pragma unroll
  for (int tt = 0; tt < 8; ++tt) {
    float s = accv[tt] + bias;
    float sp = (s > 20.f) ? s : log1pf(__expf(s));
    dt[(size_t)(tg * 8 + tt) * 1024 + d0 + tid] = sp;
  }
}

// ---------- scan pass 1: per-chunk decay product P and local end-state H ----------
// grid 512: b(4) x dgroup(16) x chunk(8); block 256 = 64 d x 4 state-quads
__global__ __launch_bounds__(256) void k_scan1(
    const float* __restrict__ dt, const float* __restrict__ xc,
    const float* __restrict__ xdb, const float* __restrict__ alog,
    float* __restrict__ sP, float* __restrict__ sH) {
  int bid = blockIdx.x;
  int b = bid >> 7, dg = (bid >> 3) & 15, c = bid & 7;
  int tid = threadIdx.x, dl = tid >> 2, sq = tid & 3;
  int d = dg * 64 + dl;
  int t0 = b * 512 + c * 64;
  __shared__ float ldt[16][64], lxc[16][64], lB[16][16];
  f32x4 al = *reinterpret_cast<const f32x4*>(alog + (size_t)d * 16 + sq * 4);
  float A[4], h[4] = {}, P[4] = {1.f, 1.f, 1.f, 1.f};
  #pragma unroll
  for (int j = 0; j < 4; ++j) A[j] = -__expf(al[j]);
  for (int tile = 0; tile < 4; ++tile) {
    int tt = t0 + tile * 16;
    __syncthreads();
    {
      int row = tid >> 4, f4 = (tid & 15) * 4;
      *reinterpret_cast<f32x4*>(&ldt[row][f4]) =
          *reinterpret_cast<const f32x4*>(dt + (size_t)(tt + row) * 1024 + dg * 64 + f4);
      *reinterpret_cast<f32x4*>(&lxc[row][f4]) =
          *reinterpret_cast<const f32x4*>(xc + (size_t)(tt + row) * 1024 + dg * 64 + f4);
    }
    if (tid < 64) {
      int row = tid >> 2, f4 = (tid & 3) * 4;
      *reinterpret_cast<f32x4*>(&lB[row][f4]) =
          *reinterpret_cast<const f32x4*>(xdb + (size_t)(tt + row) * 64 + 32 + f4);
    }
    __syncthreads();
    for (int lr = 0; lr < 16; ++lr) {
      float dtv = ldt[lr][dl];
      float dtx = dtv * lxc[lr][dl];
      f32x4 Bv = *reinterpret_cast<const f32x4*>(&lB[lr][sq * 4]);
      #pragma unroll
      for (int j = 0; j < 4; ++j) {
        float e = __expf(dtv * A[j]);
        h[j] = h[j] * e + dtx * Bv[j];
        P[j] *= e;
      }
    }
  }
  size_t base = ((size_t)(c * 4 + b) * 1024 + d) * 16 + sq * 4;
  *reinterpret_cast<f32x4*>(sP + base) = (f32x4){P[0], P[1], P[2], P[3]};
  *reinterpret_cast<f32x4*>(sH + base) = (f32x4){h[0], h[1], h[2], h[3]};
}

// ---------- scan pass 2: combine chunk states, replay emitting y, fuse D-skip + silu(z) gate, bf16 out ----------
__global__ __launch_bounds__(256) void k_scan3(
    const float* __restrict__ dt, const float* __restrict__ xc,
    const float* __restrict__ xdb, const float* __restrict__ alog,
    const float* __restrict__ sP, const float* __restrict__ sH,
    const float* __restrict__ xz, const float* __restrict__ Dw,
    u16* __restrict__ ygb) {
  int bid = blockIdx.x;
  int b = bid >> 7, dg = (bid >> 3) & 15, c = bid & 7;
  int tid = threadIdx.x, dl = tid >> 2, sq = tid & 3;
  int d = dg * 64 + dl;
  int t0 = b * 512 + c * 64;
  __shared__ float ldt[16][64], lxc[16][64], lB[16][16], lC[16][16], ly[16][64];
  f32x4 al = *reinterpret_cast<const f32x4*>(alog + (size_t)d * 16 + sq * 4);
  float A[4], h[4] = {};
  #pragma unroll
  for (int j = 0; j < 4; ++j) A[j] = -__expf(al[j]);
  {
    size_t base = ((size_t)b * 1024 + d) * 16 + sq * 4;
    for (int cc = 0; cc < c; ++cc) {
      f32x4 Pp = *reinterpret_cast<const f32x4*>(sP + (size_t)cc * 65536 + base);
      f32x4 Hh = *reinterpret_cast<const f32x4*>(sH + (size_t)cc * 65536 + base);
      #pragma unroll
      for (int j = 0; j < 4; ++j) h[j] = Pp[j] * h[j] + Hh[j];
    }
  }
  for (int tile = 0; tile < 4; ++tile) {
    int tt = t0 + tile * 16;
    __syncthreads();
    {
      int row = tid >> 4, f4 = (tid & 15) * 4;
      *reinterpret_cast<f32x4*>(&ldt[row][f4]) =
          *reinterpret_cast<const f32x4*>(dt + (size_t)(tt + row) * 1024 + dg * 64 + f4);
      *reinterpret_cast<f32x4*>(&lxc[row][f4]) =
          *reinterpret_cast<const f32x4*>(xc + (size_t)(tt + row) * 1024 + dg * 64 + f4);
    }
    if (tid < 64) {
      int row = tid >> 2, f4 = (tid & 3) * 4;
      *reinterpret_cast<f32x4*>(&lB[row][f4]) =
          *reinterpret_cast<const f32x4*>(xdb + (size_t)(tt + row) * 64 + 32 + f4);
    } else if (tid < 128) {
      int t2 = tid - 64;
      int row = t2 >> 2, f4 = (t2 & 3) * 4;
      *reinterpret_cast<f32x4*>(&lC[row][f4]) =
          *reinterpret_cast<const f32x4*>(xdb + (size_t)(tt + row) * 64 + 48 + f4);
    }
    __syncthreads();
    for (int lr = 0; lr < 16; ++lr) {
      float dtv = ldt[lr][dl];
      float dtx = dtv * lxc[lr][dl];
      f32x4 Bv = *reinterpret_cast<const f32x4*>(&lB[lr][sq * 4]);
      f32x4 Cv = *reinterpret_cast<const f32x4*>(&lC[lr][sq * 4]);
      float py = 0.f;
      #pragma unroll
      for (int j = 0; j < 4; ++j) {
        float e = __expf(dtv * A[j]);
        h[j] = h[j] * e + dtx * Bv[j];
        py += h[j] * Cv[j];
      }
      py += __shfl_xor(py, 1);
      py += __shfl_xor(py, 2);
      if (sq == 0) ly[lr][dl] = py;
    }
    __syncthreads();
    {
      int row = tid >> 4, f4 = (tid & 15) * 4;
      f32x4 y4 = *reinterpret_cast<f32x4*>(&ly[row][f4]);
      f32x4 x4 = *reinterpret_cast<f32x4*>(&lxc[row][f4]);
      f32x4 z4 = *reinterpret_cast<const f32x4*>(xz + (size_t)(tt + row) * 2048 + 1024 + dg * 64 + f4);
      f32x4 D4 = *reinterpret_cast<const f32x4*>(Dw + dg * 64 + f4);
      u16x4 o;
      #pragma unroll
      for (int j = 0; j < 4; ++j) {
        float yv = y4[j] + x4[j] * D4[j];
        float zz = z4[j];
        float g = zz / (1.f + __expf(-zz));
        o[j] = f2bf(yv * g);
      }
      *reinterpret_cast<u16x4*>(ygb + (size_t)(tt + row) * 1024 + dg * 64 + f4) = o;
    }
  }
}

// ---------- GLU: ml = y * silu(gate) (bf16 in/out) ----------
__global__ void k_glu_bf(const u16* __restrict__ fgb, u16* __restrict__ mlb) {
  int i4 = blockIdx.x * 256 + threadIdx.x;
  int t = i4 >> 9, n4 = (i4 & 511) * 4;
  u16x4 ya = *reinterpret_cast<const u16x4*>(fgb + (size_t)t * 4096 + n4);
  u16x4 ga = *reinterpret_cast<const u16x4*>(fgb + (size_t)t * 4096 + 2048 + n4);
  u16x4 o;
  #pragma unroll
  for (int j = 0; j < 4; ++j) {
    float y = bf2f(ya[j]), g = bf2f(ga[j]);
    float s = g / (1.f + __expf(-g));
    o[j] = f2bf(y * s);
  }
  *reinterpret_cast<u16x4*>(mlb + (size_t)t * 2048 + n4) = o;
}

// ---------- mean pool (2-stage) + head ----------
__global__ void k_pool1(const float* __restrict__ xn, float* __restrict__ part) {
  int b = blockIdx.x >> 4, lc = blockIdx.x & 15;
  int tid = threadIdx.x;
  float s0 = 0.f, s1 = 0.f;
  for (int l = lc * 32; l < lc * 32 + 32; ++l) {
    const float* row = xn + (size_t)(b * 512 + l) * 512;
    s0 += row[tid];
    s1 += row[tid + 256];
  }
  part[(size_t)blockIdx.x * 512 + tid] = s0;
  part[(size_t)blockIdx.x * 512 + tid + 256] = s1;
}

__global__ void k_pool2(const float* __restrict__ part, float* __restrict__ pooled) {
  int idx = blockIdx.x * 256 + threadIdx.x;
  int b = idx >> 9, dm = idx & 511;
  float s = 0.f;
  for (int lc = 0; lc < 16; ++lc) s += part[(size_t)(b * 16 + lc) * 512 + dm];
  pooled[idx] = s * (1.f / 512.f);
}

__global__ void k_head(const float* __restrict__ pooled, const float* __restrict__ hw,
                       const float* __restrict__ hb, float* __restrict__ out) {
  int b = blockIdx.x / 50, c = blockIdx.x % 50;
  int lane = threadIdx.x;
  float s = 0.f;
  #pragma unroll
  for (int q = 0; q < 8; ++q) {
    int dm = q * 64 + lane;
    s += pooled[b * 512 + dm] * hw[(size_t)c * 512 + dm];
  }
  for (int m = 32; m; m >>= 1) s += __shfl_xor(s, m);
  if (lane == 0) out[b * 50 + c] = s + hb[c];
}

// ---------- launch ----------
extern "C" void kernel_launch(void* const* d_in, const int* in_sizes, int n_in,
                              void* d_out, int out_size, void* d_ws, size_t ws_size,
                              hipStream_t stream) {
  (void)in_sizes; (void)n_in; (void)out_size; (void)ws_size;
  const float* x      = (const float*)d_in[0];
  const float* emb_w  = (const float*)d_in[1];
  const float* emb_b  = (const float*)d_in[2];
  const float* inp_w  = (const float*)d_in[3];
  const float* conv_w = (const float*)d_in[4];
  const float* conv_b = (const float*)d_in[5];
  const float* xp_w   = (const float*)d_in[6];
  const float* dt_w   = (const float*)d_in[7];
  const float* dt_b   = (const float*)d_in[8];
  const float* a_log  = (const float*)d_in[9];
  const float* Dw     = (const float*)d_in[10];
  const float* outp_w = (const float*)d_in[11];
  const float* n1_w   = (const float*)d_in[12];
  const float* n2_w   = (const float*)d_in[13];
  const float* fc1_w  = (const float*)d_in[14];
  const float* fc2_w  = (const float*)d_in[15];
  const float* nf_w   = (const float*)d_in[16];
  const float* head_w = (const float*)d_in[17];
  const float* head_b = (const float*)d_in[18];

  float* fp = (float*)d_ws;
  float* resid  = fp;
  float* hid    = fp + 1048576;
  float* xn     = fp + 2097152;
  float* xz     = fp + 3145728;   // T x 2048
  float* xc     = fp + 7340032;   // T x 1024
  float* dtbuf  = fp + 9437184;   // T x 1024
  float* xdb    = fp + 11534336;  // T x 64
  float* sP     = fp + 11665408;  // 8 x 4 x 1024 x 16
  float* sH     = fp + 12189696;
  float* part   = fp + 12713984;  // 64 x 512
  float* pooled = fp + 12746752;  // 2048
  u16* us  = (u16*)(fp + 12748800);
  u16* fgb = us;                  // T x 4096 bf16
  u16* xb  = us + 8388608;        // T x 128
  u16* xnb = us + 8650752;        // T x 512
  u16* ygb = us + 9699328;        // T x 1024
  u16* mlb = us + 11796480;       // T x 2048
  u16* wbh = us + 15990784;       // 4718592 per-layer weight hi
  u16* wbl = us + 20709376;       // 4718592 per-layer weight lo

  hipMemsetAsync(resid, 0, (size_t)1048576 * 4, stream);
  k_cvt<<<256, 256, 0, stream>>>(x, xb);
  k_cvtsplit<<<64, 256, 0, stream>>>(emb_w, wbh, wbl);
  gemm_bf<2, 2><<<dim3(8, 32), 256, 0, stream>>>(xb, 128, wbh, wbl, 128, (void*)hid, 512, 128, emb_b, 1);

  for (int i = 0; i < 12; ++i) {
    k_wcvt<<<4608, 256, 0, stream>>>(inp_w + (size_t)i * 1048576, outp_w + (size_t)i * 524288,
                                     fc1_w + (size_t)i * 2097152, fc2_w + (size_t)i * 1048576,
                                     wbh, wbl);
    k_addnorm<<<2048, 256, 0, stream>>>(resid, hid, n1_w + i * 512, xn, xnb);
    gemm_bf<4, 4><<<dim3(16, 16), 256, 0, stream>>>(xnb, 512, wbh, wbl, 512,
                                                    (void*)xz, 2048, 512, nullptr, 0);
    k_conv<<<8192, 256, 0, stream>>>(xz, conv_w + (size_t)i * 4096, conv_b + i * 1024, xc);
    k_xdb<<<512, 256, 0, stream>>>(xc, xp_w + (size_t)i * 65536, xdb);
    k_dt<<<dim3(256, 4), 256, 0, stream>>>(xdb, dt_w + (size_t)i * 32768, dt_b + i * 1024, dtbuf);
    k_scan1<<<512, 256, 0, stream>>>(dtbuf, xc, xdb, a_log + (size_t)i * 16384, sP, sH);
    k_scan3<<<512, 256, 0, stream>>>(dtbuf, xc, xdb, a_log + (size_t)i * 16384, sP, sH,
                                     xz, Dw + i * 1024, ygb);
    gemm_bf<2, 2><<<dim3(8, 32), 256, 0, stream>>>(ygb, 1024, wbh + 1048576, wbl + 1048576, 1024,
                                                   (void*)hid, 512, 1024, nullptr, 0);
    k_addnorm<<<2048, 256, 0, stream>>>(resid, hid, n2_w + i * 512, xn, xnb);
    gemm_bf<4, 4><<<dim3(32, 16), 256, 0, stream>>>(xnb, 512, wbh + 1572864, wbl + 1572864, 512,
                                                    (void*)fgb, 4096, 512, nullptr, 2);
    k_glu_bf<<<4096, 256, 0, stream>>>(fgb, mlb);
    gemm_bf<2, 2><<<dim3(8, 32), 256, 0, stream>>>(mlb, 2048, wbh + 3670016, wbl + 3670016, 2048,
                                                   (void*)hid, 512, 2048, nullptr, 0);
  }

  k_addnorm<<<2048, 256, 0, stream>>>(resid, hid, nf_w, xn, xnb);
  k_pool1<<<64, 256, 0, stream>>>(xn, part);
  k_pool2<<<8, 256, 0, stream>>>(part, pooled);
  k_head<<<200, 64, 0, stream>>>(pooled, head_w, head_b, (float*)d_out);
}